// Round 1
// baseline (354.911 us; speedup 1.0000x reference)
//
#include <hip/hip_runtime.h>

// B=4, P=12000, C=64, NX=NY=512
//   in[0]: pillar_embeddings float32 [B,P,C]
//   in[1]: pillar_coords     int32   [B,P,2]  (ix, iy)
//   in[2]: pillar_mask       int32   [B,P]
//   out:   float32 [B, C, NY, NX]
//
// Strategy: the output is 97.7% zeros (12000 candidate cells of 262144 per
// batch, mask ~50%). Split the work into its two true components:
//   Phase A: pure zero-fill of the 256 MB output. Zero loads in the loop ->
//            no vmcnt serialization of the store stream -> runs at the
//            fill-kernel ceiling (~6.4 TB/s, like rocclr fillBuffer).
//   Phase B: direct sparse scatter of the ~24k valid pillars. One wave per
//            pillar: coalesced 256 B embedding-row read (1 dword/lane),
//            then each lane NT-stores its channel to out[b][c=lane][iy][ix].
//            Wave-uniform mask exit -> no divergence. ~6 MB payload.
// This removes the cell->pillar map entirely (no init/scatter passes, no
// 4 MB map traffic) and removes all loads from the 256 MB write stream.
#define NXc 512
#define NYc 512
#define Bc  4
#define Pc  12000
#define Cc  64
#define CELLS (NXc * NYc)                    // 262144 cells per batch
#define OUT_FV4 (Bc * Cc * (CELLS / 4))      // 16,777,216 float4 = 256 MB

typedef float fv4 __attribute__((ext_vector_type(4)));

// Phase A: grid-strided NT float4 zero-fill. 2048 blocks (8/CU) x 256 thr,
// 32 stores/thread, each wave-store = 1 KB contiguous. Fire-and-forget:
// no loads -> no waitcnt in the loop -> store stream saturates HBM.
__global__ void __launch_bounds__(256)
zero_fill_kernel(fv4* __restrict__ out4) {
    const fv4 z = {0.0f, 0.0f, 0.0f, 0.0f};
    size_t i = (size_t)blockIdx.x * blockDim.x + threadIdx.x;
    const size_t stride = (size_t)gridDim.x * blockDim.x;
    #pragma unroll 4
    for (; i < (size_t)OUT_FV4; i += stride)
        __builtin_nontemporal_store(z, out4 + i);
}

// Phase B: one wave per (b, p) pillar. 4 waves / 256-thread block.
// grid = B*P/4 = 12000 blocks exactly.
__global__ void __launch_bounds__(256)
pillar_scatter_kernel(const float* __restrict__ emb,
                      const int* __restrict__ coords,
                      const int* __restrict__ mask,
                      float* __restrict__ out) {
    const int g    = blockIdx.x * 4 + (threadIdx.x >> 6);  // global pillar id
    const int lane = threadIdx.x & 63;                     // channel c

    // broadcast load (all 64 lanes same address), wave-uniform branch
    if (mask[g] <= 0) return;

    const int ix = coords[2 * g];
    const int iy = coords[2 * g + 1];
    const int b  = g / Pc;
    const int cell = iy * NXc + ix;

    // coalesced: lanes read 64 consecutive floats of this pillar's row
    const float v = emb[(size_t)g * Cc + lane];

    // scatter: lane c writes out[b][c][iy][ix]; addresses 1 MB apart across
    // lanes -> 64 partial-line bursts. NT: bypass L2, avoid dirtying 1.5M
    // cache lines (would cost ~196 MB of whole-line writebacks on evict).
    __builtin_nontemporal_store(
        v, out + (size_t)(b * Cc + lane) * CELLS + cell);
}

extern "C" void kernel_launch(void* const* d_in, const int* in_sizes, int n_in,
                              void* d_out, int out_size, void* d_ws, size_t ws_size,
                              hipStream_t stream) {
    const float* emb  = (const float*)d_in[0];
    const int* coords = (const int*)d_in[1];
    const int* mask   = (const int*)d_in[2];
    float* out        = (float*)d_out;

    zero_fill_kernel<<<2048, 256, 0, stream>>>((fv4*)out);
    pillar_scatter_kernel<<<Bc * Pc / 4, 256, 0, stream>>>(emb, coords, mask, out);
}

// Round 2
// 281.210 us; speedup vs baseline: 1.2621x; 1.2621x over previous
//
#include <hip/hip_runtime.h>

// B=4, P=12000, C=64, NX=NY=512
//   in[0]: pillar_embeddings float32 [B,P,C]
//   in[1]: pillar_coords     int32   [B,P,2]  (ix, iy)
//   in[2]: pillar_mask       int32   [B,P]
//   out:   float32 [B, C, NY, NX]
//
// Round-2 strategy: fused dense write (round-0) was right; scattered 4B NT
// stores (round-1) were catastrophic (1.5M partial-line RMW transactions).
// Fix round-0's real defect instead: loads inside the store loop serialize
// the 256 MB store stream on the single in-order vmcnt counter. So:
//   - one thread per CELL (not per 4 cells): read map entry, and if occupied
//     (~4.6% of lanes) preload the full 64-float emb row into 16 float4 regs
//     BEFORE the store loop.
//   - store loop = 64 NT dword stores from registers, ZERO loads -> pure
//     fire-and-forget store stream at fill-kernel rate. Each wave store is
//     256 B contiguous; grid coverage is dense full lines.
#define NXc 512
#define NYc 512
#define Bc  4
#define Pc  12000
#define Cc  64
#define CELLS (NXc * NYc)          // 262144 cells per batch (2^18)
#define MAPN  (Bc * CELLS)         // 1,048,576 map entries (4 MB)

typedef float fv4 __attribute__((ext_vector_type(4)));

__global__ void map_scatter_kernel(const int* __restrict__ coords,
                                   const int* __restrict__ mask,
                                   int* __restrict__ map) {
    const int p = blockIdx.x * blockDim.x + threadIdx.x;   // global pillar id
    if (p >= Bc * Pc) return;
    if (mask[p] <= 0) return;
    const int ix = coords[2 * p];
    const int iy = coords[2 * p + 1];
    const int b = p / Pc;
    map[b * CELLS + iy * NXc + ix] = p;    // cells unique per batch -> no race
}

// One thread per cell. t == b*CELLS + cell (CELLS = 2^18).
__global__ void __launch_bounds__(256)
bev_gather_kernel(const float* __restrict__ emb,
                  const int* __restrict__ map,
                  float* __restrict__ out) {
    const int t    = blockIdx.x * blockDim.x + threadIdx.x;  // MAPN threads
    const int cell = t & (CELLS - 1);
    const int b    = t >> 18;
    const int m    = map[t];               // coalesced 4B/lane

    // ---- load phase: everything the store loop needs, into registers ----
    fv4 v[16];
    #pragma unroll
    for (int i = 0; i < 16; ++i) v[i] = (fv4){0.f, 0.f, 0.f, 0.f};
    if (m >= 0) {                          // ~4.6% of lanes; exec-masked
        const fv4* e = (const fv4*)(emb + (size_t)m * Cc);
        #pragma unroll
        for (int i = 0; i < 16; ++i) v[i] = e[i];
    }

    // ---- store phase: 64 dense NT dword stores, no loads, no waits ----
    float* op = out + (size_t)b * Cc * CELLS + cell;
    #pragma unroll
    for (int i = 0; i < 16; ++i) {
        __builtin_nontemporal_store(v[i].x, op);  op += CELLS;
        __builtin_nontemporal_store(v[i].y, op);  op += CELLS;
        __builtin_nontemporal_store(v[i].z, op);  op += CELLS;
        __builtin_nontemporal_store(v[i].w, op);  op += CELLS;
    }
}

extern "C" void kernel_launch(void* const* d_in, const int* in_sizes, int n_in,
                              void* d_out, int out_size, void* d_ws, size_t ws_size,
                              hipStream_t stream) {
    const float* emb  = (const float*)d_in[0];
    const int* coords = (const int*)d_in[1];
    const int* mask   = (const int*)d_in[2];
    float* out        = (float*)d_out;
    int* map          = (int*)d_ws;          // 4 MB scratch

    hipMemsetAsync(map, 0xFF, (size_t)MAPN * sizeof(int), stream);  // -1 fill
    map_scatter_kernel<<<(Bc * Pc + 255) / 256, 256, 0, stream>>>(coords, mask, map);
    bev_gather_kernel<<<MAPN / 256, 256, 0, stream>>>(emb, map, out);
}

// Round 3
// 276.857 us; speedup vs baseline: 1.2819x; 1.0157x over previous
//
#include <hip/hip_runtime.h>

// B=4, P=12000, C=64, NX=NY=512
//   in[0]: pillar_embeddings float32 [B,P,C]
//   in[1]: pillar_coords     int32   [B,P,2]  (ix, iy)
//   in[2]: pillar_mask       int32   [B,P]
//   out:   float32 [B, C, NY, NX]
//
// Round-3 theory: rounds 0/2 both ran the 256 MB store stream at ~2.4 TB/s
// because each thread stepped the c-dimension at a 1 MB power-of-2 stride
// (aggregate stream = 64 interleaved strided slabs). The rocclr fill hits
// 6.35 TB/s with a SEQUENTIAL stream. Fix: thread index == linear output
// float4 index. Lanes cover consecutive cells at fixed (b,c); consecutive
// blocks sweep consecutive output addresses -> sequential store streams.
// Map entries are re-read once per channel (64x) but stay L2-resident
// (4 MB); emb rows (12 MB) stay L2-resident; empty lanes clamp to the
// pillar-0 row (one broadcast line) and are zeroed by select.
#define NXc 512
#define NYc 512
#define Bc  4
#define Pc  12000
#define Cc  64
#define CELLS (NXc * NYc)            // 262144 cells per batch (2^18)
#define MAPN  (Bc * CELLS)           // 1,048,576 map entries (4 MB)
#define OUT_FV4 (Bc * Cc * (CELLS / 4))   // 16,777,216 float4

typedef float fv4 __attribute__((ext_vector_type(4)));
typedef int   iv4 __attribute__((ext_vector_type(4)));

__global__ void map_scatter_kernel(const int* __restrict__ coords,
                                   const int* __restrict__ mask,
                                   int* __restrict__ map) {
    const int p = blockIdx.x * blockDim.x + threadIdx.x;   // global pillar id
    if (p >= Bc * Pc) return;
    if (mask[p] <= 0) return;
    const int ix = coords[2 * p];
    const int iy = coords[2 * p + 1];
    const int b = p / Pc;
    map[b * CELLS + iy * NXc + ix] = p;    // cells unique per batch -> no race
}

// One thread per output float4, t == linear fv4 index.
// t = (b*64 + c) * 65536 + cell4   (65536 = CELLS/4 fv4 per c-plane)
__global__ void __launch_bounds__(256)
bev_gather_kernel(const float* __restrict__ emb,
                  const iv4* __restrict__ map4,
                  fv4* __restrict__ out4) {
    const int t     = blockIdx.x * blockDim.x + threadIdx.x;  // 0..OUT_FV4
    const int cell4 = t & (CELLS / 4 - 1);       // 0..65535
    const int plane = t >> 16;                   // b*64 + c
    const int c     = plane & (Cc - 1);
    const int b     = plane >> 6;

    // coalesced 16B/lane; L2-resident after first c-plane touches it
    const iv4 m = map4[(size_t)b * (CELLS / 4) + cell4];

    // clamped scalar gathers (empty lanes read broadcast pillar-0 line)
    const float x0 = emb[(size_t)(m.x < 0 ? 0 : m.x) * Cc + c];
    const float x1 = emb[(size_t)(m.y < 0 ? 0 : m.y) * Cc + c];
    const float x2 = emb[(size_t)(m.z < 0 ? 0 : m.z) * Cc + c];
    const float x3 = emb[(size_t)(m.w < 0 ? 0 : m.w) * Cc + c];

    fv4 v;
    v.x = (m.x >= 0) ? x0 : 0.0f;
    v.y = (m.y >= 0) ? x1 : 0.0f;
    v.z = (m.z >= 0) ? x2 : 0.0f;
    v.w = (m.w >= 0) ? x3 : 0.0f;

    // store address == thread index: aggregate stream is sequential.
    // NT: write-only 256 MB, keep map/emb resident in L2.
    __builtin_nontemporal_store(v, out4 + t);
}

extern "C" void kernel_launch(void* const* d_in, const int* in_sizes, int n_in,
                              void* d_out, int out_size, void* d_ws, size_t ws_size,
                              hipStream_t stream) {
    const float* emb  = (const float*)d_in[0];
    const int* coords = (const int*)d_in[1];
    const int* mask   = (const int*)d_in[2];
    float* out        = (float*)d_out;
    int* map          = (int*)d_ws;          // 4 MB scratch

    hipMemsetAsync(map, 0xFF, (size_t)MAPN * sizeof(int), stream);  // -1 fill
    map_scatter_kernel<<<(Bc * Pc + 255) / 256, 256, 0, stream>>>(coords, mask, map);
    bev_gather_kernel<<<OUT_FV4 / 256, 256, 0, stream>>>(emb, (const iv4*)map,
                                                         (fv4*)out);
}